// Round 4
// baseline (1258.694 us; speedup 1.0000x reference)
//
#include <hip/hip_runtime.h>
#include <math.h>

// ContextualLoss: X,T = reshape(50,16384)[10:50]; column-cosine S = Xn^T Tn
// (K=40 contraction); per input-column i: m=min_j S, M=max_j S,
// Z = sum_j exp((1 - S/(m+eps))/H); CXmax_i = max(w(m),w(M))/Z (w monotone in S);
// loss = -log(max_i CXmax_i).

#define NCOL   16384          // c*w = 128*128
#define KDIM   40             // rows 10..49
#define ROW0   10
#define EPSILON 1e-5f
#define HINV    5.0f          // 1/h, h = 0.2
#define COS_EPS 1e-8f
#define JSPLIT  32
#define JCHUNK  (NCOL / JSPLIT)   // 512

// ---------------- kernel 1: mu + column normalize ----------------
// one thread per column n. Writes:
//   xn (k-major, [40][16384])  -> coalesced per-k reads in hot kernels
//   tn (j-major, [16384][40])  -> 160B rows, wave-uniform float4 reads
__global__ void ctx_norm_kernel(const float* __restrict__ inp,
                                const float* __restrict__ tgt,
                                float* __restrict__ xn,
                                float* __restrict__ tn) {
    int n = blockIdx.x * blockDim.x + threadIdx.x;
    if (n >= NCOL) return;
    float t[KDIM], x[KDIM];
    float mu = 0.f;
#pragma unroll
    for (int r = 0; r < KDIM; ++r) {
        t[r] = tgt[(ROW0 + r) * NCOL + n];
        mu += t[r];
    }
    mu *= (1.0f / KDIM);
    float nt = 0.f;
#pragma unroll
    for (int r = 0; r < KDIM; ++r) { t[r] -= mu; nt = fmaf(t[r], t[r], nt); }
    float rnt = 1.0f / fmaxf(sqrtf(nt), COS_EPS);
#pragma unroll
    for (int r = 0; r < KDIM; ++r) tn[n * KDIM + r] = t[r] * rnt;

    float nx = 0.f;
#pragma unroll
    for (int r = 0; r < KDIM; ++r) {
        x[r] = inp[(ROW0 + r) * NCOL + n] - mu;
        nx = fmaf(x[r], x[r], nx);
    }
    float rnx = 1.0f / fmaxf(sqrtf(nx), COS_EPS);
#pragma unroll
    for (int r = 0; r < KDIM; ++r) xn[r * NCOL + n] = x[r] * rnx;
}

// dot(x[40], tn row j) with 4 independent FMA chains, float4 b-loads
// (b address is wave-uniform -> scalarizable).
__device__ __forceinline__ float ctx_dot40(const float x[KDIM],
                                           const float* __restrict__ tn, int j) {
    const float4* bp = reinterpret_cast<const float4*>(tn + j * KDIM);
    float s0 = 0.f, s1 = 0.f, s2 = 0.f, s3 = 0.f;
#pragma unroll
    for (int q = 0; q < KDIM / 4; ++q) {
        float4 b = bp[q];
        s0 = fmaf(x[4 * q + 0], b.x, s0);
        s1 = fmaf(x[4 * q + 1], b.y, s1);
        s2 = fmaf(x[4 * q + 2], b.z, s2);
        s3 = fmaf(x[4 * q + 3], b.w, s3);
    }
    return (s0 + s1) + (s2 + s3);
}

// ---------------- kernel 2: row min/max over a j-chunk ----------------
// grid (64, JSPLIT), block 256. thread -> column i; scans JCHUNK j's.
__global__ __launch_bounds__(256) void ctx_stats_kernel(
        const float* __restrict__ xn, const float* __restrict__ tn,
        float* __restrict__ pmin, float* __restrict__ pmax) {
    int i  = blockIdx.x * 256 + threadIdx.x;
    int js = blockIdx.y;
    float x[KDIM];
#pragma unroll
    for (int k = 0; k < KDIM; ++k) x[k] = xn[k * NCOL + i];

    float mn = 3.4e38f, mx = -3.4e38f;
    int j0 = js * JCHUNK;
    for (int j = j0; j < j0 + JCHUNK; ++j) {
        float s = ctx_dot40(x, tn, j);
        mn = fminf(mn, s);
        mx = fmaxf(mx, s);
    }
    pmin[js * NCOL + i] = mn;
    pmax[js * NCOL + i] = mx;
}

// ---------------- kernel 3: row sum of exp over a j-chunk ----------------
__global__ __launch_bounds__(256) void ctx_sumexp_kernel(
        const float* __restrict__ xn, const float* __restrict__ tn,
        const float* __restrict__ pmin, float* __restrict__ psum) {
    int i  = blockIdx.x * 256 + threadIdx.x;
    int js = blockIdx.y;

    float m = pmin[i];
#pragma unroll
    for (int s = 1; s < JSPLIT; ++s) m = fminf(m, pmin[s * NCOL + i]);
    float c = 1.0f / (m + EPSILON);

    float x[KDIM];
#pragma unroll
    for (int k = 0; k < KDIM; ++k) x[k] = xn[k * NCOL + i];

    float acc = 0.f;
    int j0 = js * JCHUNK;
    for (int j = j0; j < j0 + JCHUNK; ++j) {
        float s = ctx_dot40(x, tn, j);
        acc += __expf((1.0f - s * c) * HINV);
    }
    psum[js * NCOL + i] = acc;
}

// ---------------- kernel 4: finalize -> scalar loss ----------------
__global__ void ctx_final_kernel(const float* __restrict__ pmin,
                                 const float* __restrict__ pmax,
                                 const float* __restrict__ psum,
                                 float* __restrict__ out) {
    int tid = threadIdx.x;
    float best = 0.0f;  // CX values are strictly positive
    for (int i = tid; i < NCOL; i += 256) {
        float m = pmin[i], M = pmax[i], Z = 0.f;
#pragma unroll
        for (int s = 1; s < JSPLIT; ++s) {
            m = fminf(m, pmin[s * NCOL + i]);
            M = fmaxf(M, pmax[s * NCOL + i]);
        }
#pragma unroll
        for (int s = 0; s < JSPLIT; ++s) Z += psum[s * NCOL + i];
        float c  = 1.0f / (m + EPSILON);
        // w is monotone in S -> row max of w is at one of the S extremes
        float w1 = __expf((1.0f - M * c) * HINV);
        float w2 = __expf((1.0f - m * c) * HINV);
        best = fmaxf(best, fmaxf(w1, w2) / Z);
    }
    // wave reduce (64 lanes) then cross-wave via LDS
    for (int off = 32; off > 0; off >>= 1)
        best = fmaxf(best, __shfl_down(best, off, 64));
    __shared__ float red[4];
    if ((tid & 63) == 0) red[tid >> 6] = best;
    __syncthreads();
    if (tid == 0) {
        float b = fmaxf(fmaxf(red[0], red[1]), fmaxf(red[2], red[3]));
        out[0] = -logf(b);
    }
}

extern "C" void kernel_launch(void* const* d_in, const int* in_sizes, int n_in,
                              void* d_out, int out_size, void* d_ws, size_t ws_size,
                              hipStream_t stream) {
    const float* inp = (const float*)d_in[0];   // input          (5,10,128,128) f32
    const float* tgt = (const float*)d_in[1];   // target_features same shape
    float* out = (float*)d_out;

    // workspace layout (floats):
    //   xn   : 40*16384           = 655360
    //   tn   : 16384*40           = 655360
    //   pmin : JSPLIT*16384       = 524288
    //   pmax : JSPLIT*16384       = 524288
    //   psum : JSPLIT*16384       = 524288
    // total ~ 2.88M floats = 11.5 MB
    float* ws   = (float*)d_ws;
    float* xn   = ws;
    float* tn   = xn + (size_t)KDIM * NCOL;
    float* pmin = tn + (size_t)NCOL * KDIM;
    float* pmax = pmin + (size_t)JSPLIT * NCOL;
    float* psum = pmax + (size_t)JSPLIT * NCOL;

    ctx_norm_kernel<<<NCOL / 256, 256, 0, stream>>>(inp, tgt, xn, tn);
    dim3 grid(NCOL / 256, JSPLIT);
    ctx_stats_kernel<<<grid, 256, 0, stream>>>(xn, tn, pmin, pmax);
    ctx_sumexp_kernel<<<grid, 256, 0, stream>>>(xn, tn, pmin, psum);
    ctx_final_kernel<<<1, 256, 0, stream>>>(pmin, pmax, psum, out);
}

// Round 5
// 748.298 us; speedup vs baseline: 1.6821x; 1.6821x over previous
//
#include <hip/hip_runtime.h>
#include <math.h>

// ContextualLoss: X,T = reshape(50,16384)[10:50]; column-cosine S = Xn^T Tn
// (K=40 contraction); per input-column i: m=min_j S, M=max_j S,
// Z = sum_j exp((1 - S/(m+eps))/H); CXmax_i = max(w(m),w(M))/Z (w monotone in S);
// loss = -log(max_i CXmax_i).

#define NCOL   16384          // c*w = 128*128
#define KDIM   40             // rows 10..49
#define ROW0   10
#define EPSILON 1e-5f
#define HINV    5.0f          // 1/h, h = 0.2
#define COS_EPS 1e-8f
#define JSPLIT  32
#define JCHUNK  (NCOL / JSPLIT)   // 512
#define NBLK_I  (NCOL / 256)      // 64

// ---------------- kernel 1: mu + column normalize ----------------
// one thread per column n. Writes:
//   xn (k-major, [40][16384])  -> coalesced per-k reads in hot kernels
//   tn (j-major, [16384][40])  -> 160B rows, wave-uniform float4 reads
__global__ void ctx_norm_kernel(const float* __restrict__ inp,
                                const float* __restrict__ tgt,
                                float* __restrict__ xn,
                                float* __restrict__ tn) {
    int n = blockIdx.x * blockDim.x + threadIdx.x;
    if (n >= NCOL) return;
    float t[KDIM], x[KDIM];
    float mu = 0.f;
#pragma unroll
    for (int r = 0; r < KDIM; ++r) {
        t[r] = tgt[(ROW0 + r) * NCOL + n];
        mu += t[r];
    }
    mu *= (1.0f / KDIM);
    float nt = 0.f;
#pragma unroll
    for (int r = 0; r < KDIM; ++r) { t[r] -= mu; nt = fmaf(t[r], t[r], nt); }
    float rnt = 1.0f / fmaxf(sqrtf(nt), COS_EPS);
#pragma unroll
    for (int r = 0; r < KDIM; ++r) tn[n * KDIM + r] = t[r] * rnt;

    float nx = 0.f;
#pragma unroll
    for (int r = 0; r < KDIM; ++r) {
        x[r] = inp[(ROW0 + r) * NCOL + n] - mu;
        nx = fmaf(x[r], x[r], nx);
    }
    float rnx = 1.0f / fmaxf(sqrtf(nx), COS_EPS);
#pragma unroll
    for (int r = 0; r < KDIM; ++r) xn[r * NCOL + n] = x[r] * rnx;
}

// dot(x[40], tn row j) with 4 independent FMA chains, float4 b-loads
// (b address is wave-uniform -> scalarizable / broadcast, L1-hit).
__device__ __forceinline__ float ctx_dot40(const float x[KDIM],
                                           const float* __restrict__ tn, int j) {
    const float4* bp = reinterpret_cast<const float4*>(tn + j * KDIM);
    float s0 = 0.f, s1 = 0.f, s2 = 0.f, s3 = 0.f;
#pragma unroll
    for (int q = 0; q < KDIM / 4; ++q) {
        float4 b = bp[q];
        s0 = fmaf(x[4 * q + 0], b.x, s0);
        s1 = fmaf(x[4 * q + 1], b.y, s1);
        s2 = fmaf(x[4 * q + 2], b.z, s2);
        s3 = fmaf(x[4 * q + 3], b.w, s3);
    }
    return (s0 + s1) + (s2 + s3);
}

// ---------------- kernel 2: row min/max over a j-chunk ----------------
// grid (64, JSPLIT), block 256. thread -> column i; scans JCHUNK j's.
__global__ __launch_bounds__(256) void ctx_stats_kernel(
        const float* __restrict__ xn, const float* __restrict__ tn,
        float* __restrict__ pmin, float* __restrict__ pmax) {
    int i  = blockIdx.x * 256 + threadIdx.x;
    int js = blockIdx.y;
    float x[KDIM];
#pragma unroll
    for (int k = 0; k < KDIM; ++k) x[k] = xn[k * NCOL + i];

    float mn = 3.4e38f, mx = -3.4e38f;
    int j0 = js * JCHUNK;
    for (int j = j0; j < j0 + JCHUNK; ++j) {
        float s = ctx_dot40(x, tn, j);
        mn = fminf(mn, s);
        mx = fmaxf(mx, s);
    }
    pmin[js * NCOL + i] = mn;
    pmax[js * NCOL + i] = mx;
}

// ---------------- kernel 3: row sum of exp over a j-chunk ----------------
__global__ __launch_bounds__(256) void ctx_sumexp_kernel(
        const float* __restrict__ xn, const float* __restrict__ tn,
        const float* __restrict__ pmin, float* __restrict__ psum) {
    int i  = blockIdx.x * 256 + threadIdx.x;
    int js = blockIdx.y;

    float m = pmin[i];
#pragma unroll
    for (int s = 1; s < JSPLIT; ++s) m = fminf(m, pmin[s * NCOL + i]);
    float c = 1.0f / (m + EPSILON);

    float x[KDIM];
#pragma unroll
    for (int k = 0; k < KDIM; ++k) x[k] = xn[k * NCOL + i];

    float acc = 0.f;
    int j0 = js * JCHUNK;
    for (int j = j0; j < j0 + JCHUNK; ++j) {
        float s = ctx_dot40(x, tn, j);
        acc += __expf((1.0f - s * c) * HINV);
    }
    psum[js * NCOL + i] = acc;
}

// ---------------- kernel 4a: per-column CX-max, block-level max ----------------
// grid 64 blocks x 256 threads: thread -> column i (full coverage, coalesced
// stride-NCOL partial reads). Writes one max per block.
__global__ __launch_bounds__(256) void ctx_reduce_kernel(
        const float* __restrict__ pmin, const float* __restrict__ pmax,
        const float* __restrict__ psum, float* __restrict__ blkmax) {
    int tid = threadIdx.x;
    int i = blockIdx.x * 256 + tid;

    float m = pmin[i], M = pmax[i], Z = psum[i];
#pragma unroll
    for (int s = 1; s < JSPLIT; ++s) {
        m = fminf(m, pmin[s * NCOL + i]);
        M = fmaxf(M, pmax[s * NCOL + i]);
        Z += psum[s * NCOL + i];
    }
    float c  = 1.0f / (m + EPSILON);
    // w is monotone in S -> row max of w is at one of the S extremes
    float w1 = __expf((1.0f - M * c) * HINV);
    float w2 = __expf((1.0f - m * c) * HINV);
    float best = fmaxf(w1, w2) / Z;   // CX strictly positive

    // wave reduce (64 lanes) then cross-wave via LDS
    for (int off = 32; off > 0; off >>= 1)
        best = fmaxf(best, __shfl_down(best, off, 64));
    __shared__ float red[4];
    if ((tid & 63) == 0) red[tid >> 6] = best;
    __syncthreads();
    if (tid == 0)
        blkmax[blockIdx.x] = fmaxf(fmaxf(red[0], red[1]), fmaxf(red[2], red[3]));
}

// ---------------- kernel 4b: 64 -> 1, -log ----------------
__global__ void ctx_loss_kernel(const float* __restrict__ blkmax,
                                float* __restrict__ out) {
    int tid = threadIdx.x;       // one wave of 64
    float best = blkmax[tid];
    for (int off = 32; off > 0; off >>= 1)
        best = fmaxf(best, __shfl_down(best, off, 64));
    if (tid == 0) out[0] = -logf(best);
}

extern "C" void kernel_launch(void* const* d_in, const int* in_sizes, int n_in,
                              void* d_out, int out_size, void* d_ws, size_t ws_size,
                              hipStream_t stream) {
    const float* inp = (const float*)d_in[0];   // input          (5,10,128,128) f32
    const float* tgt = (const float*)d_in[1];   // target_features same shape
    float* out = (float*)d_out;

    // workspace layout (floats):
    //   xn     : 40*16384      = 655360
    //   tn     : 16384*40      = 655360
    //   pmin   : JSPLIT*16384  = 524288
    //   pmax   : JSPLIT*16384  = 524288
    //   psum   : JSPLIT*16384  = 524288
    //   blkmax : 64
    // total ~ 2.88M floats = 11.5 MB
    float* ws     = (float*)d_ws;
    float* xn     = ws;
    float* tn     = xn + (size_t)KDIM * NCOL;
    float* pmin   = tn + (size_t)NCOL * KDIM;
    float* pmax   = pmin + (size_t)JSPLIT * NCOL;
    float* psum   = pmax + (size_t)JSPLIT * NCOL;
    float* blkmax = psum + (size_t)JSPLIT * NCOL;

    ctx_norm_kernel<<<NCOL / 256, 256, 0, stream>>>(inp, tgt, xn, tn);
    dim3 grid(NBLK_I, JSPLIT);
    ctx_stats_kernel<<<grid, 256, 0, stream>>>(xn, tn, pmin, pmax);
    ctx_sumexp_kernel<<<grid, 256, 0, stream>>>(xn, tn, pmin, psum);
    ctx_reduce_kernel<<<NBLK_I, 256, 0, stream>>>(pmin, pmax, psum, blkmax);
    ctx_loss_kernel<<<1, 64, 0, stream>>>(blkmax, out);
}

// Round 6
// 169.452 us; speedup vs baseline: 7.4280x; 4.4160x over previous
//
#include <hip/hip_runtime.h>
#include <math.h>

// ContextualLoss via MFMA bf16.
// X,T = reshape(50,16384)[10:50]; S = Xn^T Tn (K=40 padded to 64, bf16 MFMA);
// per input-column i: m=min_j S, M=max_j S, Z=sum_j exp((1-S/(m+eps))/h);
// CXmax_i = max(w(m),w(M))/Z (w monotone in S); loss = -log(max_i CXmax_i).

#define NCOL   16384
#define KDIM   40
#define KPAD   64
#define ROW0   10
#define EPSILON 1e-5f
#define COS_EPS 1e-8f
#define Q5L2E   7.2134752044448169f   // 5 * log2(e)  (1/h = 5)
#define JS      16                    // j slices
#define JSL     (NCOL / JS)           // 1024 j per slice
#define JT_PER  (JSL / 16)            // 64 16-wide j tiles per wave

typedef __attribute__((ext_vector_type(8))) short bf16x8;
typedef __attribute__((ext_vector_type(4))) float f32x4;

static __device__ __forceinline__ unsigned short f2bf(float f) {
    unsigned u = __float_as_uint(f);           // RNE float->bf16
    u += 0x7FFFu + ((u >> 16) & 1u);
    return (unsigned short)(u >> 16);
}

// ---------------- kernel 1: mu + column normalize + bf16 pack ----------------
// thread n -> column n. Writes xb[i][64], tb[j][64] bf16, k-padded with zeros.
__global__ __launch_bounds__(256) void ctx_norm_kernel(
        const float* __restrict__ inp, const float* __restrict__ tgt,
        short* __restrict__ xb, short* __restrict__ tb) {
    int n = blockIdx.x * 256 + threadIdx.x;
    float t[KDIM], x[KDIM];
    float mu = 0.f;
#pragma unroll
    for (int r = 0; r < KDIM; ++r) { t[r] = tgt[(ROW0 + r) * NCOL + n]; mu += t[r]; }
    mu *= (1.0f / KDIM);
    float nt = 0.f;
#pragma unroll
    for (int r = 0; r < KDIM; ++r) { t[r] -= mu; nt = fmaf(t[r], t[r], nt); }
    float rnt = 1.0f / fmaxf(sqrtf(nt), COS_EPS);
    float nx = 0.f;
#pragma unroll
    for (int r = 0; r < KDIM; ++r) {
        x[r] = inp[(ROW0 + r) * NCOL + n] - mu;
        nx = fmaf(x[r], x[r], nx);
    }
    float rnx = 1.0f / fmaxf(sqrtf(nx), COS_EPS);

    short* to = tb + (size_t)n * KPAD;
    short* xo = xb + (size_t)n * KPAD;
#pragma unroll
    for (int q = 0; q < KDIM / 4; ++q) {        // q = 0..9: data
        ushort4 wt, wx;
        wt.x = f2bf(t[4*q+0] * rnt); wt.y = f2bf(t[4*q+1] * rnt);
        wt.z = f2bf(t[4*q+2] * rnt); wt.w = f2bf(t[4*q+3] * rnt);
        wx.x = f2bf(x[4*q+0] * rnx); wx.y = f2bf(x[4*q+1] * rnx);
        wx.z = f2bf(x[4*q+2] * rnx); wx.w = f2bf(x[4*q+3] * rnx);
        *reinterpret_cast<ushort4*>(to + 4*q) = wt;
        *reinterpret_cast<ushort4*>(xo + 4*q) = wx;
    }
    ushort4 z = {0, 0, 0, 0};
#pragma unroll
    for (int q = KDIM / 4; q < KPAD / 4; ++q) { // q = 10..15: zero pad
        *reinterpret_cast<ushort4*>(to + 4*q) = z;
        *reinterpret_cast<ushort4*>(xo + 4*q) = z;
    }
}

// ---------------- kernel 2: MFMA row min/max over a j slice ----------------
// grid (64, JS), 256 thr = 4 waves. Wave owns 64 i-rows (4 MFMA M-subtiles),
// scans JSL j's. A-frags register-resident; B-frags straight from global
// (wave-span 1KB, L1/L2-hit). C/D layout: col=lane&15, row=(lane>>4)*4+reg.
__global__ __launch_bounds__(256, 4) void ctx_stats_kernel(
        const short* __restrict__ xb, const short* __restrict__ tb,
        float* __restrict__ pmin, float* __restrict__ pmax) {
    const int tid = threadIdx.x;
    const int wave = tid >> 6, l = tid & 63;
    const int la = l & 15, g = l >> 4;
    const int ibase = blockIdx.x * 256 + wave * 64;
    const int js = blockIdx.y;

    bf16x8 a[4][2];
#pragma unroll
    for (int mi = 0; mi < 4; ++mi)
#pragma unroll
        for (int ks = 0; ks < 2; ++ks)
            a[mi][ks] = *reinterpret_cast<const bf16x8*>(
                xb + (size_t)(ibase + mi * 16 + la) * KPAD + ks * 32 + g * 8);

    float vmn[4][4], vmx[4][4];
#pragma unroll
    for (int mi = 0; mi < 4; ++mi)
#pragma unroll
        for (int r = 0; r < 4; ++r) { vmn[mi][r] = 3.4e38f; vmx[mi][r] = -3.4e38f; }

    const f32x4 zero4 = {0.f, 0.f, 0.f, 0.f};
    const short* bp = tb + (size_t)(js * JSL + la) * KPAD + g * 8;
#pragma unroll 2
    for (int jt = 0; jt < JT_PER; ++jt) {
        bf16x8 b0 = *reinterpret_cast<const bf16x8*>(bp);
        bf16x8 b1 = *reinterpret_cast<const bf16x8*>(bp + 32);
        bp += 16 * KPAD;
#pragma unroll
        for (int mi = 0; mi < 4; ++mi) {
            f32x4 acc = __builtin_amdgcn_mfma_f32_16x16x32_bf16(a[mi][0], b0, zero4, 0, 0, 0);
            acc = __builtin_amdgcn_mfma_f32_16x16x32_bf16(a[mi][1], b1, acc, 0, 0, 0);
#pragma unroll
            for (int r = 0; r < 4; ++r) {
                vmn[mi][r] = fminf(vmn[mi][r], acc[r]);
                vmx[mi][r] = fmaxf(vmx[mi][r], acc[r]);
            }
        }
    }
    // reduce over the 16 column-lanes of each 16-lane group
#pragma unroll
    for (int off = 1; off < 16; off <<= 1)
#pragma unroll
        for (int mi = 0; mi < 4; ++mi)
#pragma unroll
            for (int r = 0; r < 4; ++r) {
                vmn[mi][r] = fminf(vmn[mi][r], __shfl_xor(vmn[mi][r], off, 64));
                vmx[mi][r] = fmaxf(vmx[mi][r], __shfl_xor(vmx[mi][r], off, 64));
            }
    if (la == 0) {
#pragma unroll
        for (int mi = 0; mi < 4; ++mi)
#pragma unroll
            for (int r = 0; r < 4; ++r) {
                int row = ibase + mi * 16 + g * 4 + r;
                pmin[js * NCOL + row] = vmn[mi][r];
                pmax[js * NCOL + row] = vmx[mi][r];
            }
    }
}

// ---------------- kernel 3: fold JS partials -> final row min/max ----------------
__global__ __launch_bounds__(256) void ctx_fold_kernel(
        const float* __restrict__ pmin, const float* __restrict__ pmax,
        float* __restrict__ rmin, float* __restrict__ rmax) {
    int i = blockIdx.x * 256 + threadIdx.x;
    float m = pmin[i], M = pmax[i];
#pragma unroll
    for (int s = 1; s < JS; ++s) {
        m = fminf(m, pmin[s * NCOL + i]);
        M = fmaxf(M, pmax[s * NCOL + i]);
    }
    rmin[i] = m; rmax[i] = M;
}

// ---------------- kernel 4: MFMA row sum of exp over a j slice ----------------
// w = exp((1-S*c)/h) = exp2(fma(S, -Q5L2E*c, Q5L2E)), c = 1/(m+eps) per row.
__global__ __launch_bounds__(256, 4) void ctx_sumexp_kernel(
        const short* __restrict__ xb, const short* __restrict__ tb,
        const float* __restrict__ rmin, float* __restrict__ psum) {
    const int tid = threadIdx.x;
    const int wave = tid >> 6, l = tid & 63;
    const int la = l & 15, g = l >> 4;
    const int ibase = blockIdx.x * 256 + wave * 64;
    const int js = blockIdx.y;

    bf16x8 a[4][2];
#pragma unroll
    for (int mi = 0; mi < 4; ++mi)
#pragma unroll
        for (int ks = 0; ks < 2; ++ks)
            a[mi][ks] = *reinterpret_cast<const bf16x8*>(
                xb + (size_t)(ibase + mi * 16 + la) * KPAD + ks * 32 + g * 8);

    float p[4][4], zs[4][4];
#pragma unroll
    for (int mi = 0; mi < 4; ++mi)
#pragma unroll
        for (int r = 0; r < 4; ++r) {
            int row = ibase + mi * 16 + g * 4 + r;
            float c = 1.0f / (rmin[row] + EPSILON);
            p[mi][r] = -Q5L2E * c;
            zs[mi][r] = 0.f;
        }

    const f32x4 zero4 = {0.f, 0.f, 0.f, 0.f};
    const short* bp = tb + (size_t)(js * JSL + la) * KPAD + g * 8;
#pragma unroll 2
    for (int jt = 0; jt < JT_PER; ++jt) {
        bf16x8 b0 = *reinterpret_cast<const bf16x8*>(bp);
        bf16x8 b1 = *reinterpret_cast<const bf16x8*>(bp + 32);
        bp += 16 * KPAD;
#pragma unroll
        for (int mi = 0; mi < 4; ++mi) {
            f32x4 acc = __builtin_amdgcn_mfma_f32_16x16x32_bf16(a[mi][0], b0, zero4, 0, 0, 0);
            acc = __builtin_amdgcn_mfma_f32_16x16x32_bf16(a[mi][1], b1, acc, 0, 0, 0);
#pragma unroll
            for (int r = 0; r < 4; ++r)
                zs[mi][r] += exp2f(fmaf(acc[r], p[mi][r], Q5L2E));
        }
    }
#pragma unroll
    for (int off = 1; off < 16; off <<= 1)
#pragma unroll
        for (int mi = 0; mi < 4; ++mi)
#pragma unroll
            for (int r = 0; r < 4; ++r)
                zs[mi][r] += __shfl_xor(zs[mi][r], off, 64);
    if (la == 0) {
#pragma unroll
        for (int mi = 0; mi < 4; ++mi)
#pragma unroll
            for (int r = 0; r < 4; ++r) {
                int row = ibase + mi * 16 + g * 4 + r;
                psum[js * NCOL + row] = zs[mi][r];
            }
    }
}

// ---------------- kernel 5: per-row CX-max, per-block max ----------------
__global__ __launch_bounds__(256) void ctx_reduce_kernel(
        const float* __restrict__ rmin, const float* __restrict__ rmax,
        const float* __restrict__ psum, float* __restrict__ blkmax) {
    int tid = threadIdx.x;
    int i = blockIdx.x * 256 + tid;
    float m = rmin[i], M = rmax[i], Z = psum[i];
#pragma unroll
    for (int s = 1; s < JS; ++s) Z += psum[s * NCOL + i];
    float c = 1.0f / (m + EPSILON);
    float w1 = exp2f(fmaf(M, -Q5L2E * c, Q5L2E));
    float w2 = exp2f(fmaf(m, -Q5L2E * c, Q5L2E));
    float best = fmaxf(w1, w2) / Z;   // CX strictly positive

    for (int off = 32; off > 0; off >>= 1)
        best = fmaxf(best, __shfl_down(best, off, 64));
    __shared__ float red[4];
    if ((tid & 63) == 0) red[tid >> 6] = best;
    __syncthreads();
    if (tid == 0)
        blkmax[blockIdx.x] = fmaxf(fmaxf(red[0], red[1]), fmaxf(red[2], red[3]));
}

// ---------------- kernel 6: 64 -> 1, -log ----------------
__global__ void ctx_loss_kernel(const float* __restrict__ blkmax,
                                float* __restrict__ out) {
    int tid = threadIdx.x;       // one wave of 64
    float best = blkmax[tid];
    for (int off = 32; off > 0; off >>= 1)
        best = fmaxf(best, __shfl_down(best, off, 64));
    if (tid == 0) out[0] = -logf(best);
}

extern "C" void kernel_launch(void* const* d_in, const int* in_sizes, int n_in,
                              void* d_out, int out_size, void* d_ws, size_t ws_size,
                              hipStream_t stream) {
    const float* inp = (const float*)d_in[0];
    const float* tgt = (const float*)d_in[1];
    float* out = (float*)d_out;

    // ws layout (bytes):
    //   xb     bf16 [16384][64]  2 MB
    //   tb     bf16 [16384][64]  2 MB
    //   pmin   f32  [16][16384]  1 MB
    //   pmax   f32  [16][16384]  1 MB
    //   psum   f32  [16][16384]  1 MB
    //   rmin   f32  [16384]      64 KB
    //   rmax   f32  [16384]      64 KB
    //   blkmax f32  [64]
    char* base = (char*)d_ws;
    short* xb     = (short*)(base);
    short* tb     = (short*)(base + (size_t)2 * NCOL * KPAD);           // +2MB
    float* pmin   = (float*)(base + (size_t)4 * NCOL * KPAD);           // +4MB
    float* pmax   = pmin + (size_t)JS * NCOL;
    float* psum   = pmax + (size_t)JS * NCOL;
    float* rmin   = psum + (size_t)JS * NCOL;
    float* rmax   = rmin + NCOL;
    float* blkmax = rmax + NCOL;

    dim3 grid2(NCOL / 256, JS);
    ctx_norm_kernel  <<<NCOL / 256, 256, 0, stream>>>(inp, tgt, xb, tb);
    ctx_stats_kernel <<<grid2, 256, 0, stream>>>(xb, tb, pmin, pmax);
    ctx_fold_kernel  <<<NCOL / 256, 256, 0, stream>>>(pmin, pmax, rmin, rmax);
    ctx_sumexp_kernel<<<grid2, 256, 0, stream>>>(xb, tb, rmin, psum);
    ctx_reduce_kernel<<<NCOL / 256, 256, 0, stream>>>(rmin, rmax, psum, blkmax);
    ctx_loss_kernel  <<<1, 64, 0, stream>>>(blkmax, out);
}